// Round 5
// baseline (307.546 us; speedup 1.0000x reference)
//
#include <hip/hip_runtime.h>
#include <hip/hip_bf16.h>
#include <math.h>

// Problem constants (DeepseekV3MoE reference)
#define T_TOK 2048
#define H_DIM 1024
#define E_EXP 16
#define K_TOP 4
#define G_GRP 4
#define I_SZ 512
#define SCALE_F 2.5f

typedef __attribute__((ext_vector_type(8))) short bfrag;    // 8 bf16 (4 VGPR)
typedef __attribute__((ext_vector_type(8))) short short8v;
typedef __attribute__((ext_vector_type(4))) float f32x4;    // MFMA acc / NT loads

#define MFMA16(a, b, c) __builtin_amdgcn_mfma_f32_16x16x32_bf16(a, b, c, 0, 0, 0)

__device__ __forceinline__ short f2bf(float f) {
    union { float f; unsigned u; } v; v.f = f;
    unsigned u = v.u;
    u += 0x7fffu + ((u >> 16) & 1u);   // RNE
    return (short)(u >> 16);
}

// XOR-swizzled LDS index for 64-short rows: 8 segments of 8 shorts (16 B),
// physical segment = logical_seg ^ (row & 7). Conflict-free (verified: 0).
__device__ __forceinline__ int lds_idx(int row, int k) {
    return row * 64 + ((((k >> 3) ^ (row & 7))) << 3) + (k & 7);
}

// global -> LDS direct DMA, 16 B per lane; LDS dest = wave-uniform base + lane*16,
// XOR swizzle applied on the GLOBAL source offset (lane reads seg (l&7)^(l>>3)).
typedef __attribute__((address_space(1))) unsigned int as1_u32;
typedef __attribute__((address_space(3))) unsigned int as3_u32;
__device__ __forceinline__ void gld16(const short* g, short* l) {
    __builtin_amdgcn_global_load_lds((const as1_u32*)g, (as3_u32*)l, 16, 0, 0);
}

// ---------------------------------------------------------------- routing top-k (exact fp32, jax ties)
__device__ __forceinline__ void route_token(int t, const float* lgrow,
                                            const float* __restrict__ ebias,
                                            int* __restrict__ counts,
                                            int* __restrict__ lists,
                                            float* __restrict__ lweights) {
    float scores[E_EXP], sc[E_EXP];
    for (int e = 0; e < E_EXP; ++e) {
        float s = 1.f / (1.f + expf(-lgrow[e]));
        scores[e] = s;
        sc[e] = s + ebias[e];
    }
    float gs[G_GRP];
    for (int g = 0; g < G_GRP; ++g) {
        float v[4] = { sc[g*4], sc[g*4+1], sc[g*4+2], sc[g*4+3] };
        float b1 = -1e30f; int i1 = -1;
        for (int j = 0; j < 4; ++j) if (v[j] > b1) { b1 = v[j]; i1 = j; }
        float b2 = -1e30f;
        for (int j = 0; j < 4; ++j) if (j != i1 && v[j] > b2) b2 = v[j];
        gs[g] = b1 + b2;
    }
    int g1 = -1; float b1 = -1e30f;
    for (int g = 0; g < G_GRP; ++g) if (gs[g] > b1) { b1 = gs[g]; g1 = g; }
    int g2 = -1; float b2 = -1e30f;
    for (int g = 0; g < G_GRP; ++g) if (g != g1 && gs[g] > b2) { b2 = gs[g]; g2 = g; }

    float masked[E_EXP];
    for (int e = 0; e < E_EXP; ++e) {
        int grp = e >> 2;
        masked[e] = (grp == g1 || grp == g2) ? sc[e] : 0.f;
    }
    int tidx[K_TOP]; float tw[K_TOP];
    for (int k = 0; k < K_TOP; ++k) {
        int bi = -1; float bv = -1e30f;
        for (int e = 0; e < E_EXP; ++e) if (masked[e] > bv) { bv = masked[e]; bi = e; }
        tidx[k] = bi;
        tw[k] = scores[bi];
        masked[bi] = -1e30f;
    }
    float sum = tw[0] + tw[1] + tw[2] + tw[3];
    float inv = SCALE_F / (sum + 1e-20f);
    for (int k = 0; k < K_TOP; ++k) {
        int e = tidx[k];
        int pos = atomicAdd(&counts[e], 1);
        lists[e * T_TOK + pos] = t;
        lweights[e * T_TOK + pos] = tw[k] * inv;
    }
}

// ---------------------------------------------------------------- prep: convert + router + zero-out
// blocks [0, CVT_BLKS): fp32->bf16 convert (16 elem/thread, NT loads)
// blocks [CVT_BLKS, CVT_BLKS+RT_BLKS): router, 8 tokens/block
// blocks [CVT_BLKS+RT_BLKS, +ZERO_BLKS): zero d_out
#define CVT_BLKS 7424
#define RT_BLKS 256
#define ZERO_BLKS 512
#define RTOK 8

__global__ __launch_bounds__(256)
void prep_kernel(const float* __restrict__ x, const float* __restrict__ rw,
                 const float* __restrict__ ebias,
                 const float* __restrict__ g, const float* __restrict__ u,
                 const float* __restrict__ d, const float* __restrict__ sg,
                 const float* __restrict__ su, const float* __restrict__ sd,
                 short* __restrict__ go, short* __restrict__ uo, short* __restrict__ dd,
                 short* __restrict__ sgo, short* __restrict__ suo, short* __restrict__ sdo,
                 short* __restrict__ xo,
                 int* __restrict__ counts, int* __restrict__ lists,
                 float* __restrict__ lweights,
                 float* __restrict__ out, int out_n) {
    const int bx = blockIdx.x, tid = threadIdx.x;

    if (bx < CVT_BLKS) {
        long i = ((long)bx * 256 + tid) * 16;
        const float* src; short* dst; long off;
        if      (i < 8388608)  { src = g;  dst = go;  off = i; }
        else if (i < 16777216) { src = u;  dst = uo;  off = i - 8388608; }
        else if (i < 25165824) { src = d;  dst = dd;  off = i - 16777216; }
        else if (i < 26214400) { src = sg; dst = sgo; off = i - 25165824; }
        else if (i < 27262976) { src = su; dst = suo; off = i - 26214400; }
        else if (i < 28311552) { src = sd; dst = sdo; off = i - 27262976; }
        else                   { src = x;  dst = xo;  off = i - 28311552; }
        const f32x4* s4 = (const f32x4*)(src + off);
        f32x4 a = __builtin_nontemporal_load(s4);
        f32x4 b = __builtin_nontemporal_load(s4 + 1);
        f32x4 c = __builtin_nontemporal_load(s4 + 2);
        f32x4 e = __builtin_nontemporal_load(s4 + 3);
        short8v o0 = { f2bf(a[0]), f2bf(a[1]), f2bf(a[2]), f2bf(a[3]),
                       f2bf(b[0]), f2bf(b[1]), f2bf(b[2]), f2bf(b[3]) };
        short8v o1 = { f2bf(c[0]), f2bf(c[1]), f2bf(c[2]), f2bf(c[3]),
                       f2bf(e[0]), f2bf(e[1]), f2bf(e[2]), f2bf(e[3]) };
        *(short8v*)(dst + off) = o0;
        *(short8v*)(dst + off + 8) = o1;
        return;
    }

    if (bx >= CVT_BLKS + RT_BLKS) {
        // zero d_out
        int zb = bx - (CVT_BLKS + RT_BLKS);
        long idx = ((long)zb * 256 + tid) * 16;
        if (idx < out_n) {
            f32x4 z = {0.f, 0.f, 0.f, 0.f};
            f32x4* o4 = (f32x4*)(out + idx);
            o4[0] = z; o4[1] = z; o4[2] = z; o4[3] = z;
        }
        return;
    }

    // ---- router: 8 tokens, 256 threads; thread = (half, expert, token)
    __shared__ float part[256];
    __shared__ float lg[RTOK][E_EXP];
    const int t0 = (bx - CVT_BLKS) * RTOK;
    {
        int half = tid >> 7;
        int e    = (tid >> 3) & 15;
        int tok  = tid & 7;
        const float* wr = rw + (size_t)e * H_DIM + half * 512;
        const float* xr = x + (size_t)(t0 + tok) * H_DIM + half * 512;
        float acc = 0.f;
        #pragma unroll 4
        for (int k = 0; k < 512; k += 4) {
            float4 w  = *(const float4*)(wr + k);
            float4 xv = *(const float4*)(xr + k);
            acc += w.x * xv.x + w.y * xv.y + w.z * xv.z + w.w * xv.w;
        }
        part[tid] = acc;
    }
    __syncthreads();
    if (tid < 128) lg[tid & 7][tid >> 3] = part[tid] + part[tid + 128];
    __syncthreads();
    if (tid >= RTOK) return;
    route_token(t0 + tid, lg[tid], ebias, counts, lists, lweights);
}

// ---------------------------------------------------------------- Kernel A: gate+up+silu -> h
// 64 tokens x 128 i-cols per block; K=1024 in 64-chunks; gld16 staging.
// bx < 2048: routed (e=bx>>7, mt=(bx>>2)&31, nt=bx&3); else shared (256 blocks).
__global__ __launch_bounds__(256)
void moe_gateup(const short* __restrict__ Xbf,
                const int* __restrict__ counts, const int* __restrict__ lists,
                const short* __restrict__ gw, const short* __restrict__ uw,
                const short* __restrict__ sgw, const short* __restrict__ suw,
                short* __restrict__ h_r, short* __restrict__ h_sh) {
    __shared__ __align__(16) short Xs[64*64];     // 8 KB
    __shared__ __align__(16) short Gs[128*64];    // 16 KB
    __shared__ __align__(16) short Us[128*64];    // 16 KB
    __shared__ int toks[64];
    const int bx = blockIdx.x, tid = threadIdx.x;
    const short *gbase, *ubase; short* hout; int hpitch;
    if (bx < 2048) {
        int e = bx >> 7, mt = (bx >> 2) & 31, nt = bx & 3;
        int cnt = counts[e];
        if (mt * 64 >= cnt) return;
        if (tid < 64) {
            int j = mt * 64 + tid;
            toks[tid] = (j < cnt) ? lists[e * T_TOK + j] : lists[e * T_TOK];
        }
        gbase = gw + (size_t)e * I_SZ * H_DIM + (size_t)(nt * 128) * H_DIM;
        ubase = uw + (size_t)e * I_SZ * H_DIM + (size_t)(nt * 128) * H_DIM;
        hout  = h_r + ((size_t)e * T_TOK + mt * 64) * I_SZ + nt * 128;
        hpitch = I_SZ;
    } else {
        int b2 = bx - 2048, mt = b2 >> 3, nt = b2 & 7;
        if (tid < 64) toks[tid] = mt * 64 + tid;
        gbase = sgw + (size_t)(nt * 128) * H_DIM;
        ubase = suw + (size_t)(nt * 128) * H_DIM;
        hout  = h_sh + (size_t)(mt * 64) * 1024 + nt * 128;
        hpitch = 1024;
    }
    __syncthreads();

    const int lane = tid & 63, wv = tid >> 6;
    const int mw = wv & 1, nw = wv >> 1;
    const int lr = lane & 15, lq = lane >> 4;
    const int l3 = lane >> 3, l7 = lane & 7;
    const int seg = (l7 ^ l3) * 8;

    // staging: X rows wv*16+{0,8}; G/U rows wv*32+{0,8,16,24} (8-row slabs)
    const short* xA = Xbf + (size_t)toks[wv*16 + l3] * H_DIM + seg;
    const short* xB = Xbf + (size_t)toks[wv*16 + 8 + l3] * H_DIM + seg;
    const short* gS0 = gbase + (size_t)(wv*32      + l3) * H_DIM + seg;
    const short* gS1 = gbase + (size_t)(wv*32 + 8  + l3) * H_DIM + seg;
    const short* gS2 = gbase + (size_t)(wv*32 + 16 + l3) * H_DIM + seg;
    const short* gS3 = gbase + (size_t)(wv*32 + 24 + l3) * H_DIM + seg;
    const short* uS0 = ubase + (size_t)(wv*32      + l3) * H_DIM + seg;
    const short* uS1 = ubase + (size_t)(wv*32 + 8  + l3) * H_DIM + seg;
    const short* uS2 = ubase + (size_t)(wv*32 + 16 + l3) * H_DIM + seg;
    const short* uS3 = ubase + (size_t)(wv*32 + 24 + l3) * H_DIM + seg;
    short* ldsXA = &Xs[(wv*16    ) * 64]; short* ldsXB = &Xs[(wv*16 + 8) * 64];
    short* ldsG0 = &Gs[(wv*32     ) * 64]; short* ldsG1 = &Gs[(wv*32 + 8 ) * 64];
    short* ldsG2 = &Gs[(wv*32 + 16) * 64]; short* ldsG3 = &Gs[(wv*32 + 24) * 64];
    short* ldsU0 = &Us[(wv*32     ) * 64]; short* ldsU1 = &Us[(wv*32 + 8 ) * 64];
    short* ldsU2 = &Us[(wv*32 + 16) * 64]; short* ldsU3 = &Us[(wv*32 + 24) * 64];

    f32x4 aG[2][4], aU[2][4];
    #pragma unroll
    for (int a = 0; a < 2; ++a)
        #pragma unroll
        for (int b = 0; b < 4; ++b) {
            aG[a][b] = (f32x4){0.f,0.f,0.f,0.f};
            aU[a][b] = (f32x4){0.f,0.f,0.f,0.f};
        }

    #pragma unroll
    for (int c = 0; c < 16; ++c) {
        const int kc = c * 64;
        gld16(xA + kc, ldsXA);  gld16(xB + kc, ldsXB);
        gld16(gS0 + kc, ldsG0); gld16(gS1 + kc, ldsG1);
        gld16(gS2 + kc, ldsG2); gld16(gS3 + kc, ldsG3);
        gld16(uS0 + kc, ldsU0); gld16(uS1 + kc, ldsU1);
        gld16(uS2 + kc, ldsU2); gld16(uS3 + kc, ldsU3);
        __syncthreads();
        #pragma unroll
        for (int kk = 0; kk < 64; kk += 32) {
            const int kf = kk + lq * 8;
            bfrag a0 = *(const bfrag*)&Xs[lds_idx(mw*32 + lr,      kf)];
            bfrag a1 = *(const bfrag*)&Xs[lds_idx(mw*32 + 16 + lr, kf)];
            #pragma unroll
            for (int fn = 0; fn < 4; ++fn) {
                bfrag gf = *(const bfrag*)&Gs[lds_idx(nw*64 + fn*16 + lr, kf)];
                bfrag uf = *(const bfrag*)&Us[lds_idx(nw*64 + fn*16 + lr, kf)];
                aG[0][fn] = MFMA16(a0, gf, aG[0][fn]);
                aG[1][fn] = MFMA16(a1, gf, aG[1][fn]);
                aU[0][fn] = MFMA16(a0, uf, aU[0][fn]);
                aU[1][fn] = MFMA16(a1, uf, aU[1][fn]);
            }
        }
        __syncthreads();
    }

    #pragma unroll
    for (int fm = 0; fm < 2; ++fm)
        #pragma unroll
        for (int fn = 0; fn < 4; ++fn)
            #pragma unroll
            for (int r = 0; r < 4; ++r) {
                int trow = mw*32 + fm*16 + lq*4 + r;
                int col  = nw*64 + fn*16 + lr;
                float g = aG[fm][fn][r], u = aU[fm][fn][r];
                hout[(size_t)trow * hpitch + col] = f2bf(g * u / (1.f + __expf(-g)));
            }
}

// ---------------------------------------------------------------- Kernel B: down-proj
// 64 tokens x 128 out-cols per block. bx<4096: routed (K=512, weighted atomicAdd);
// else shared (K=1024, atomicAdd w=1). out pre-zeroed by prep.
__global__ __launch_bounds__(256)
void moe_down(const short* __restrict__ h_r, const short* __restrict__ h_sh,
              const int* __restrict__ counts, const int* __restrict__ lists,
              const float* __restrict__ lw, const short* __restrict__ dw,
              const short* __restrict__ shdw, float* __restrict__ out) {
    __shared__ __align__(16) short Hs[64*64];     // 8 KB
    __shared__ __align__(16) short Ws[128*64];    // 16 KB
    __shared__ int toks[64];
    __shared__ float tws[64];
    const int bx = blockIdx.x, tid = threadIdx.x;
    const short *abase, *bbase; int apitch, K, n0;
    if (bx < 4096) {
        int e = bx >> 8, mt = (bx >> 3) & 31, nt = bx & 7;
        int cnt = counts[e];
        if (mt * 64 >= cnt) return;
        if (tid < 64) {
            int j = mt * 64 + tid;
            toks[tid] = (j < cnt) ? lists[e * T_TOK + j] : 0;
            tws[tid]  = (j < cnt) ? lw[e * T_TOK + j] : 0.f;
        }
        abase = h_r + ((size_t)e * T_TOK + mt * 64) * I_SZ;
        bbase = dw + (size_t)e * H_DIM * I_SZ + (size_t)(nt * 128) * I_SZ;
        apitch = I_SZ; K = I_SZ; n0 = nt * 128;
    } else {
        int b2 = bx - 4096, mt = b2 >> 3, nt = b2 & 7;
        if (tid < 64) { toks[tid] = mt * 64 + tid; tws[tid] = 1.f; }
        abase = h_sh + (size_t)(mt * 64) * 1024;
        bbase = shdw + (size_t)(nt * 128) * 1024;
        apitch = 1024; K = 1024; n0 = nt * 128;
    }
    __syncthreads();

    const int lane = tid & 63, wv = tid >> 6;
    const int mw = wv & 1, nw = wv >> 1;
    const int lr = lane & 15, lq = lane >> 4;
    const int l3 = lane >> 3, l7 = lane & 7;
    const int seg = (l7 ^ l3) * 8;

    const short* aA  = abase + (size_t)(wv*16     + l3) * apitch + seg;
    const short* aB  = abase + (size_t)(wv*16 + 8 + l3) * apitch + seg;
    const short* bS0 = bbase + (size_t)(wv*32      + l3) * apitch + seg;  // bpitch == apitch == K
    const short* bS1 = bbase + (size_t)(wv*32 + 8  + l3) * apitch + seg;
    const short* bS2 = bbase + (size_t)(wv*32 + 16 + l3) * apitch + seg;
    const short* bS3 = bbase + (size_t)(wv*32 + 24 + l3) * apitch + seg;
    short* ldsHA = &Hs[(wv*16    ) * 64]; short* ldsHB = &Hs[(wv*16 + 8) * 64];
    short* ldsW0 = &Ws[(wv*32     ) * 64]; short* ldsW1 = &Ws[(wv*32 + 8 ) * 64];
    short* ldsW2 = &Ws[(wv*32 + 16) * 64]; short* ldsW3 = &Ws[(wv*32 + 24) * 64];

    f32x4 acc[2][4];
    #pragma unroll
    for (int a = 0; a < 2; ++a)
        #pragma unroll
        for (int b = 0; b < 4; ++b) acc[a][b] = (f32x4){0.f,0.f,0.f,0.f};

    auto chunk = [&](int kc) {
        gld16(aA + kc, ldsHA);  gld16(aB + kc, ldsHB);
        gld16(bS0 + kc, ldsW0); gld16(bS1 + kc, ldsW1);
        gld16(bS2 + kc, ldsW2); gld16(bS3 + kc, ldsW3);
        __syncthreads();
        #pragma unroll
        for (int kk = 0; kk < 64; kk += 32) {
            const int kf = kk + lq * 8;
            bfrag a0 = *(const bfrag*)&Hs[lds_idx(mw*32 + lr,      kf)];
            bfrag a1 = *(const bfrag*)&Hs[lds_idx(mw*32 + 16 + lr, kf)];
            #pragma unroll
            for (int fn = 0; fn < 4; ++fn) {
                bfrag bf = *(const bfrag*)&Ws[lds_idx(nw*64 + fn*16 + lr, kf)];
                acc[0][fn] = MFMA16(a0, bf, acc[0][fn]);
                acc[1][fn] = MFMA16(a1, bf, acc[1][fn]);
            }
        }
        __syncthreads();
    };
    #pragma unroll
    for (int c = 0; c < 8; ++c) chunk(c * 64);
    if (K == 1024) {
        #pragma unroll
        for (int c = 8; c < 16; ++c) chunk(c * 64);
    }

    #pragma unroll
    for (int fm = 0; fm < 2; ++fm)
        #pragma unroll
        for (int fn = 0; fn < 4; ++fn)
            #pragma unroll
            for (int r = 0; r < 4; ++r) {
                int trow = mw*32 + fm*16 + lq*4 + r;
                int col  = n0 + nw*64 + fn*16 + lr;
                float w = tws[trow];
                if (w != 0.f)
                    atomicAdd(out + (size_t)toks[trow] * H_DIM + col, acc[fm][fn][r] * w);
            }
}

// ---------------------------------------------------------------- fallback (fused, fp32 weights)
__global__ void zero_kernel(float* __restrict__ out, int n4, int* __restrict__ counts) {
    int i = blockIdx.x * blockDim.x + threadIdx.x;
    if (i < n4) {
        float4 z = {0.f, 0.f, 0.f, 0.f};
        *(float4*)(out + (size_t)i * 4) = z;
    }
    if (blockIdx.x == 0 && threadIdx.x < E_EXP) counts[threadIdx.x] = 0;
}

__global__ __launch_bounds__(256)
void router_fb(const float* __restrict__ x, const float* __restrict__ rw,
               const float* __restrict__ ebias, int* __restrict__ counts,
               int* __restrict__ lists, float* __restrict__ lweights) {
    __shared__ float part[256];
    __shared__ float lg[RTOK][E_EXP];
    const int tid = threadIdx.x;
    const int t0 = blockIdx.x * RTOK;
    {
        int half = tid >> 7;
        int e    = (tid >> 3) & 15;
        int tok  = tid & 7;
        const float* wr = rw + (size_t)e * H_DIM + half * 512;
        const float* xr = x + (size_t)(t0 + tok) * H_DIM + half * 512;
        float acc = 0.f;
        #pragma unroll 4
        for (int k = 0; k < 512; k += 4) {
            float4 w  = *(const float4*)(wr + k);
            float4 xv = *(const float4*)(xr + k);
            acc += w.x * xv.x + w.y * xv.y + w.z * xv.z + w.w * xv.w;
        }
        part[tid] = acc;
    }
    __syncthreads();
    if (tid < 128) lg[tid & 7][tid >> 3] = part[tid] + part[tid + 128];
    __syncthreads();
    if (tid >= RTOK) return;
    route_token(t0 + tid, lg[tid], ebias, counts, lists, lweights);
}

__device__ __forceinline__ bfrag load_wfrag_f(const float* p) {
    float4 a = *(const float4*)(p);
    float4 b = *(const float4*)(p + 4);
    bfrag r;
    r[0]=f2bf(a.x); r[1]=f2bf(a.y); r[2]=f2bf(a.z); r[3]=f2bf(a.w);
    r[4]=f2bf(b.x); r[5]=f2bf(b.y); r[6]=f2bf(b.z); r[7]=f2bf(b.w);
    return r;
}

#define TM 32
__global__ __launch_bounds__(256)
void moe_gemm_fb(const float* __restrict__ x,
                 const float* __restrict__ gate_w, const float* __restrict__ up_w,
                 const float* __restrict__ down_w, const float* __restrict__ sh_gate,
                 const float* __restrict__ sh_up, const float* __restrict__ sh_down,
                 const int* __restrict__ counts, const int* __restrict__ lists,
                 const float* __restrict__ lweights, float* __restrict__ out) {
    const int bx = blockIdx.x;
    const int e = bx >> 6;
    const int tile = bx & 63;
    int ntok; const float *gp, *upp, *dpp; int dpitch;
    if (e < E_EXP) {
        ntok = counts[e];
        gp  = gate_w + (size_t)e * I_SZ * H_DIM;
        upp = up_w   + (size_t)e * I_SZ * H_DIM;
        dpp = down_w + (size_t)e * H_DIM * I_SZ;
        dpitch = I_SZ;
    } else {
        int s = e - E_EXP;
        ntok = T_TOK;
        gp  = sh_gate + (size_t)s * I_SZ * H_DIM;
        upp = sh_up   + (size_t)s * I_SZ * H_DIM;
        dpp = sh_down + (size_t)s * I_SZ;
        dpitch = 2 * I_SZ;
    }
    const int start = tile * TM;
    if (start >= ntok) return;

    __shared__ __align__(16) short Xs2[TM][H_DIM + 8];
    __shared__ __align__(16) short Hs2[TM][I_SZ + 8];
    __shared__ int   toks[TM];
    __shared__ float tws[TM];

    const int tid = threadIdx.x;
    if (tid < TM) {
        int j = start + tid;
        int tok = 0; float w = 0.f;
        if (j < ntok) {
            if (e < E_EXP) { tok = lists[e * T_TOK + j]; w = lweights[e * T_TOK + j]; }
            else           { tok = j;                    w = 1.0f; }
        }
        toks[tid] = tok; tws[tid] = w;
    }
    __syncthreads();
    {
        int r = tid >> 3;
        int c0 = (tid & 7) * 128;
        const float* xr = x + (size_t)toks[r] * H_DIM + c0;
        #pragma unroll
        for (int c = 0; c < 128; c += 4) {
            float4 v = *(const float4*)(xr + c);
            short4 s = { f2bf(v.x), f2bf(v.y), f2bf(v.z), f2bf(v.w) };
            *(short4*)&Xs2[r][c0 + c] = s;
        }
    }
    __syncthreads();

    const int lane = tid & 63;
    const int wv   = tid >> 6;
    const int lr   = lane & 15;
    const int lq   = lane >> 4;
    const int ko   = lq * 8;

    for (int it = 0; it < I_SZ / 64; ++it) {
        const int i0 = wv * (I_SZ / 4) + it * 16;
        const float* grow = gp  + (size_t)(i0 + lr) * H_DIM;
        const float* urow = upp + (size_t)(i0 + lr) * H_DIM;
        f32x4 aG0 = {0.f,0.f,0.f,0.f}, aU0 = {0.f,0.f,0.f,0.f};
        f32x4 aG1 = {0.f,0.f,0.f,0.f}, aU1 = {0.f,0.f,0.f,0.f};
        for (int k0 = 0; k0 < H_DIM; k0 += 32) {
            bfrag bg = load_wfrag_f(grow + k0 + ko);
            bfrag bu = load_wfrag_f(urow + k0 + ko);
            bfrag a0 = *(const bfrag*)&Xs2[lr][k0 + ko];
            bfrag a1 = *(const bfrag*)&Xs2[lr + 16][k0 + ko];
            aG0 = MFMA16(a0, bg, aG0);
            aG1 = MFMA16(a1, bg, aG1);
            aU0 = MFMA16(a0, bu, aU0);
            aU1 = MFMA16(a1, bu, aU1);
        }
        #pragma unroll
        for (int r = 0; r < 4; ++r) {
            const int trow = lq * 4 + r;
            float g0 = aG0[r], u0 = aU0[r];
            Hs2[trow][i0 + lr] = f2bf(g0 * u0 / (1.f + __expf(-g0)));
            float g1 = aG1[r], u1 = aU1[r];
            Hs2[trow + 16][i0 + lr] = f2bf(g1 * u1 / (1.f + __expf(-g1)));
        }
    }
    __syncthreads();

    for (int ct = 0; ct < H_DIM / 64; ++ct) {
        const int c0 = wv * (H_DIM / 4) + ct * 16;
        const float* drow = dpp + (size_t)(c0 + lr) * dpitch;
        f32x4 a0 = {0.f,0.f,0.f,0.f}, a1 = {0.f,0.f,0.f,0.f};
        for (int k0 = 0; k0 < I_SZ; k0 += 32) {
            bfrag bd = load_wfrag_f(drow + k0 + ko);
            bfrag h0 = *(const bfrag*)&Hs2[lr][k0 + ko];
            bfrag h1 = *(const bfrag*)&Hs2[lr + 16][k0 + ko];
            a0 = MFMA16(h0, bd, a0);
            a1 = MFMA16(h1, bd, a1);
        }
        #pragma unroll
        for (int r = 0; r < 4; ++r) {
            const int trow = lq * 4 + r;
            float w0 = tws[trow], w1 = tws[trow + 16];
            if (w0 != 0.f) atomicAdd(out + (size_t)toks[trow] * H_DIM + c0 + lr, a0[r] * w0);
            if (w1 != 0.f) atomicAdd(out + (size_t)toks[trow + 16] * H_DIM + c0 + lr, a1[r] * w1);
        }
    }
}

// ---------------------------------------------------------------- launch
extern "C" void kernel_launch(void* const* d_in, const int* in_sizes, int n_in,
                              void* d_out, int out_size, void* d_ws, size_t ws_size,
                              hipStream_t stream) {
    const float* x     = (const float*)d_in[0];
    const float* rw    = (const float*)d_in[1];
    const float* ebias = (const float*)d_in[2];
    const float* gate_w = (const float*)d_in[3];
    const float* up_w   = (const float*)d_in[4];
    const float* down_w = (const float*)d_in[5];
    const float* shg    = (const float*)d_in[6];
    const float* shu    = (const float*)d_in[7];
    const float* shd    = (const float*)d_in[8];
    float* out = (float*)d_out;

    char* ws = (char*)d_ws;
    int*   counts = (int*)ws;                       // 64 B used
    int*   lists  = (int*)(ws + 1024);              // 16*2048 ints  = 128 KB
    float* lw     = (float*)(ws + 1024 + 131072);   // 16*2048 float = 128 KB
    size_t off = 1024 + 131072 + 131072;            // 263168

    const size_t n_gu = (size_t)E_EXP * I_SZ * H_DIM;   // 8388608
    const size_t n_sh = (size_t)H_DIM * 1024;           // 1048576
    const size_t n_x  = (size_t)T_TOK * H_DIM;          // 2097152

    short* g_bf  = (short*)(ws + off); off += n_gu * 2;
    short* u_bf  = (short*)(ws + off); off += n_gu * 2;
    short* d_bf  = (short*)(ws + off); off += n_gu * 2;
    short* sg_bf = (short*)(ws + off); off += n_sh * 2;
    short* su_bf = (short*)(ws + off); off += n_sh * 2;
    short* sd_bf = (short*)(ws + off); off += n_sh * 2;
    short* x_bf  = (short*)(ws + off); off += n_x * 2;
    short* h_r   = (short*)(ws + off); off += (size_t)E_EXP * T_TOK * I_SZ * 2;  // 32 MB
    short* h_sh  = (short*)(ws + off); off += (size_t)T_TOK * 1024 * 2;          // 4 MB
    const size_t need = off;

    if (ws_size >= need) {
        hipMemsetAsync(counts, 0, 64, stream);
        prep_kernel<<<CVT_BLKS + RT_BLKS + ZERO_BLKS, 256, 0, stream>>>(
            x, rw, ebias, gate_w, up_w, down_w, shg, shu, shd,
            g_bf, u_bf, d_bf, sg_bf, su_bf, sd_bf, x_bf,
            counts, lists, lw, out, out_size);
        moe_gateup<<<2048 + 256, 256, 0, stream>>>(x_bf, counts, lists, g_bf, u_bf,
                                                   sg_bf, su_bf, h_r, h_sh);
        moe_down<<<4096 + 256, 256, 0, stream>>>(h_r, h_sh, counts, lists, lw,
                                                 d_bf, sd_bf, out);
    } else {
        zero_kernel<<<(out_size / 4 + 255) / 256, 256, 0, stream>>>(out, out_size / 4, counts);
        router_fb<<<T_TOK / RTOK, 256, 0, stream>>>(x, rw, ebias, counts, lists, lw);
        moe_gemm_fb<<<(E_EXP + 2) * 64, 256, 0, stream>>>(x, gate_w, up_w, down_w,
                                                          shg, shu, shd, counts, lists, lw, out);
    }
}

// Round 6
// 300.218 us; speedup vs baseline: 1.0244x; 1.0244x over previous
//
#include <hip/hip_runtime.h>
#include <hip/hip_bf16.h>
#include <math.h>

// Problem constants (DeepseekV3MoE reference)
#define T_TOK 2048
#define H_DIM 1024
#define E_EXP 16
#define K_TOP 4
#define G_GRP 4
#define I_SZ 512
#define SCALE_F 2.5f

typedef __attribute__((ext_vector_type(8))) short bfrag;    // 8 bf16 (4 VGPR)
typedef __attribute__((ext_vector_type(8))) short short8v;
typedef __attribute__((ext_vector_type(4))) float f32x4;    // MFMA acc

#define MFMA16(a, b, c) __builtin_amdgcn_mfma_f32_16x16x32_bf16(a, b, c, 0, 0, 0)

__device__ __forceinline__ short f2bf(float f) {
    union { float f; unsigned u; } v; v.f = f;
    unsigned u = v.u;
    u += 0x7fffu + ((u >> 16) & 1u);   // RNE
    return (short)(u >> 16);
}

// XOR-swizzled LDS index for 64-short rows: 8 segments of 8 shorts (16 B),
// physical segment = logical_seg ^ (row & 7). Conflict-free (verified: 0).
__device__ __forceinline__ int lds_idx(int row, int k) {
    return row * 64 + ((((k >> 3) ^ (row & 7))) << 3) + (k & 7);
}

// global -> LDS direct DMA, 16 B per lane; LDS dest = wave-uniform base + lane*16,
// XOR swizzle applied on the GLOBAL source offset (lane reads seg (l&7)^(l>>3)).
typedef __attribute__((address_space(1))) unsigned int as1_u32;
typedef __attribute__((address_space(3))) unsigned int as3_u32;
__device__ __forceinline__ void gld16(const short* g, short* l) {
    __builtin_amdgcn_global_load_lds((const as1_u32*)g, (as3_u32*)l, 16, 0, 0);
}

// ---------------------------------------------------------------- routing top-k (exact fp32, jax ties)
__device__ __forceinline__ void route_token(int t, const float* lgrow,
                                            const float* __restrict__ ebias,
                                            int* __restrict__ counts,
                                            int* __restrict__ lists,
                                            float* __restrict__ lweights) {
    float scores[E_EXP], sc[E_EXP];
    for (int e = 0; e < E_EXP; ++e) {
        float s = 1.f / (1.f + expf(-lgrow[e]));
        scores[e] = s;
        sc[e] = s + ebias[e];
    }
    float gs[G_GRP];
    for (int g = 0; g < G_GRP; ++g) {
        float v[4] = { sc[g*4], sc[g*4+1], sc[g*4+2], sc[g*4+3] };
        float b1 = -1e30f; int i1 = -1;
        for (int j = 0; j < 4; ++j) if (v[j] > b1) { b1 = v[j]; i1 = j; }
        float b2 = -1e30f;
        for (int j = 0; j < 4; ++j) if (j != i1 && v[j] > b2) b2 = v[j];
        gs[g] = b1 + b2;
    }
    int g1 = -1; float b1 = -1e30f;
    for (int g = 0; g < G_GRP; ++g) if (gs[g] > b1) { b1 = gs[g]; g1 = g; }
    int g2 = -1; float b2 = -1e30f;
    for (int g = 0; g < G_GRP; ++g) if (g != g1 && gs[g] > b2) { b2 = gs[g]; g2 = g; }

    float masked[E_EXP];
    for (int e = 0; e < E_EXP; ++e) {
        int grp = e >> 2;
        masked[e] = (grp == g1 || grp == g2) ? sc[e] : 0.f;
    }
    int tidx[K_TOP]; float tw[K_TOP];
    for (int k = 0; k < K_TOP; ++k) {
        int bi = -1; float bv = -1e30f;
        for (int e = 0; e < E_EXP; ++e) if (masked[e] > bv) { bv = masked[e]; bi = e; }
        tidx[k] = bi;
        tw[k] = scores[bi];
        masked[bi] = -1e30f;
    }
    float sum = tw[0] + tw[1] + tw[2] + tw[3];
    float inv = SCALE_F / (sum + 1e-20f);
    for (int k = 0; k < K_TOP; ++k) {
        int e = tidx[k];
        int pos = atomicAdd(&counts[e], 1);
        lists[e * T_TOK + pos] = t;
        lweights[e * T_TOK + pos] = tw[k] * inv;
    }
}

// ---------------------------------------------------------------- prep: convert + router + zero-out
// blocks [0, CVT_BLKS): fp32->bf16 convert (16 elem/thread, CACHED loads, 4-way MLP)
// blocks [CVT_BLKS, CVT_BLKS+RT_BLKS): router, 8 tokens/block
// blocks [CVT_BLKS+RT_BLKS, +ZERO_BLKS): zero d_out
#define CVT_BLKS 7424
#define RT_BLKS 256
#define ZERO_BLKS 512
#define RTOK 8

__global__ __launch_bounds__(256)
void prep_kernel(const float* __restrict__ x, const float* __restrict__ rw,
                 const float* __restrict__ ebias,
                 const float* __restrict__ g, const float* __restrict__ u,
                 const float* __restrict__ d, const float* __restrict__ sg,
                 const float* __restrict__ su, const float* __restrict__ sd,
                 short* __restrict__ go, short* __restrict__ uo, short* __restrict__ dd,
                 short* __restrict__ sgo, short* __restrict__ suo, short* __restrict__ sdo,
                 short* __restrict__ xo,
                 int* __restrict__ counts, int* __restrict__ lists,
                 float* __restrict__ lweights,
                 float* __restrict__ out, int out_n) {
    const int bx = blockIdx.x, tid = threadIdx.x;

    if (bx < CVT_BLKS) {
        long i = ((long)bx * 256 + tid) * 16;
        const float* src; short* dst; long off;
        if      (i < 8388608)  { src = g;  dst = go;  off = i; }
        else if (i < 16777216) { src = u;  dst = uo;  off = i - 8388608; }
        else if (i < 25165824) { src = d;  dst = dd;  off = i - 16777216; }
        else if (i < 26214400) { src = sg; dst = sgo; off = i - 25165824; }
        else if (i < 27262976) { src = su; dst = suo; off = i - 26214400; }
        else if (i < 28311552) { src = sd; dst = sdo; off = i - 27262976; }
        else                   { src = x;  dst = xo;  off = i - 28311552; }
        const float4* s4 = (const float4*)(src + off);
        float4 a  = s4[0];
        float4 b  = s4[1];
        float4 c  = s4[2];
        float4 e4 = s4[3];
        short8v o0 = { f2bf(a.x), f2bf(a.y), f2bf(a.z), f2bf(a.w),
                       f2bf(b.x), f2bf(b.y), f2bf(b.z), f2bf(b.w) };
        short8v o1 = { f2bf(c.x), f2bf(c.y), f2bf(c.z), f2bf(c.w),
                       f2bf(e4.x), f2bf(e4.y), f2bf(e4.z), f2bf(e4.w) };
        *(short8v*)(dst + off) = o0;
        *(short8v*)(dst + off + 8) = o1;
        return;
    }

    if (bx >= CVT_BLKS + RT_BLKS) {
        // zero d_out
        int zb = bx - (CVT_BLKS + RT_BLKS);
        long idx = ((long)zb * 256 + tid) * 16;
        if (idx < out_n) {
            f32x4 z = {0.f, 0.f, 0.f, 0.f};
            f32x4* o4 = (f32x4*)(out + idx);
            o4[0] = z; o4[1] = z; o4[2] = z; o4[3] = z;
        }
        return;
    }

    // ---- router: 8 tokens, 256 threads; thread = (half, expert, token)
    __shared__ float part[256];
    __shared__ float lg[RTOK][E_EXP];
    const int t0 = (bx - CVT_BLKS) * RTOK;
    {
        int half = tid >> 7;
        int e    = (tid >> 3) & 15;
        int tok  = tid & 7;
        const float* wr = rw + (size_t)e * H_DIM + half * 512;
        const float* xr = x + (size_t)(t0 + tok) * H_DIM + half * 512;
        float acc = 0.f;
        #pragma unroll 4
        for (int k = 0; k < 512; k += 4) {
            float4 w  = *(const float4*)(wr + k);
            float4 xv = *(const float4*)(xr + k);
            acc += w.x * xv.x + w.y * xv.y + w.z * xv.z + w.w * xv.w;
        }
        part[tid] = acc;
    }
    __syncthreads();
    if (tid < 128) lg[tid & 7][tid >> 3] = part[tid] + part[tid + 128];
    __syncthreads();
    if (tid >= RTOK) return;
    route_token(t0 + tid, lg[tid], ebias, counts, lists, lweights);
}

// ---------------------------------------------------------------- Kernel A: gate+up+silu -> h
// 64 tokens x 128 i-cols per block; K=1024 in 64-chunks; gld16 staging.
// bx < 2048: routed (e=bx>>7, mt=(bx>>2)&31, nt=bx&3); else shared (256 blocks).
__global__ __launch_bounds__(256)
void moe_gateup(const short* __restrict__ Xbf,
                const int* __restrict__ counts, const int* __restrict__ lists,
                const short* __restrict__ gw, const short* __restrict__ uw,
                const short* __restrict__ sgw, const short* __restrict__ suw,
                short* __restrict__ h_r, short* __restrict__ h_sh) {
    __shared__ __align__(16) short Xs[64*64];     // 8 KB
    __shared__ __align__(16) short Gs[128*64];    // 16 KB
    __shared__ __align__(16) short Us[128*64];    // 16 KB
    __shared__ int toks[64];
    const int bx = blockIdx.x, tid = threadIdx.x;
    const short *gbase, *ubase; short* hout; int hpitch;
    if (bx < 2048) {
        int e = bx >> 7, mt = (bx >> 2) & 31, nt = bx & 3;
        int cnt = counts[e];
        if (mt * 64 >= cnt) return;
        if (tid < 64) {
            int j = mt * 64 + tid;
            toks[tid] = (j < cnt) ? lists[e * T_TOK + j] : lists[e * T_TOK];
        }
        gbase = gw + (size_t)e * I_SZ * H_DIM + (size_t)(nt * 128) * H_DIM;
        ubase = uw + (size_t)e * I_SZ * H_DIM + (size_t)(nt * 128) * H_DIM;
        hout  = h_r + ((size_t)e * T_TOK + mt * 64) * I_SZ + nt * 128;
        hpitch = I_SZ;
    } else {
        int b2 = bx - 2048, mt = b2 >> 3, nt = b2 & 7;
        if (tid < 64) toks[tid] = mt * 64 + tid;
        gbase = sgw + (size_t)(nt * 128) * H_DIM;
        ubase = suw + (size_t)(nt * 128) * H_DIM;
        hout  = h_sh + (size_t)(mt * 64) * 1024 + nt * 128;
        hpitch = 1024;
    }
    __syncthreads();

    const int lane = tid & 63, wv = tid >> 6;
    const int mw = wv & 1, nw = wv >> 1;
    const int lr = lane & 15, lq = lane >> 4;
    const int l3 = lane >> 3, l7 = lane & 7;
    const int seg = (l7 ^ l3) * 8;

    const short* xA = Xbf + (size_t)toks[wv*16 + l3] * H_DIM + seg;
    const short* xB = Xbf + (size_t)toks[wv*16 + 8 + l3] * H_DIM + seg;
    const short* gS0 = gbase + (size_t)(wv*32      + l3) * H_DIM + seg;
    const short* gS1 = gbase + (size_t)(wv*32 + 8  + l3) * H_DIM + seg;
    const short* gS2 = gbase + (size_t)(wv*32 + 16 + l3) * H_DIM + seg;
    const short* gS3 = gbase + (size_t)(wv*32 + 24 + l3) * H_DIM + seg;
    const short* uS0 = ubase + (size_t)(wv*32      + l3) * H_DIM + seg;
    const short* uS1 = ubase + (size_t)(wv*32 + 8  + l3) * H_DIM + seg;
    const short* uS2 = ubase + (size_t)(wv*32 + 16 + l3) * H_DIM + seg;
    const short* uS3 = ubase + (size_t)(wv*32 + 24 + l3) * H_DIM + seg;
    short* ldsXA = &Xs[(wv*16    ) * 64]; short* ldsXB = &Xs[(wv*16 + 8) * 64];
    short* ldsG0 = &Gs[(wv*32     ) * 64]; short* ldsG1 = &Gs[(wv*32 + 8 ) * 64];
    short* ldsG2 = &Gs[(wv*32 + 16) * 64]; short* ldsG3 = &Gs[(wv*32 + 24) * 64];
    short* ldsU0 = &Us[(wv*32     ) * 64]; short* ldsU1 = &Us[(wv*32 + 8 ) * 64];
    short* ldsU2 = &Us[(wv*32 + 16) * 64]; short* ldsU3 = &Us[(wv*32 + 24) * 64];

    f32x4 aG[2][4], aU[2][4];
    #pragma unroll
    for (int a = 0; a < 2; ++a)
        #pragma unroll
        for (int b = 0; b < 4; ++b) {
            aG[a][b] = (f32x4){0.f,0.f,0.f,0.f};
            aU[a][b] = (f32x4){0.f,0.f,0.f,0.f};
        }

    #pragma unroll
    for (int c = 0; c < 16; ++c) {
        const int kc = c * 64;
        gld16(xA + kc, ldsXA);  gld16(xB + kc, ldsXB);
        gld16(gS0 + kc, ldsG0); gld16(gS1 + kc, ldsG1);
        gld16(gS2 + kc, ldsG2); gld16(gS3 + kc, ldsG3);
        gld16(uS0 + kc, ldsU0); gld16(uS1 + kc, ldsU1);
        gld16(uS2 + kc, ldsU2); gld16(uS3 + kc, ldsU3);
        __syncthreads();
        #pragma unroll
        for (int kk = 0; kk < 64; kk += 32) {
            const int kf = kk + lq * 8;
            bfrag a0 = *(const bfrag*)&Xs[lds_idx(mw*32 + lr,      kf)];
            bfrag a1 = *(const bfrag*)&Xs[lds_idx(mw*32 + 16 + lr, kf)];
            #pragma unroll
            for (int fn = 0; fn < 4; ++fn) {
                bfrag gf = *(const bfrag*)&Gs[lds_idx(nw*64 + fn*16 + lr, kf)];
                bfrag uf = *(const bfrag*)&Us[lds_idx(nw*64 + fn*16 + lr, kf)];
                aG[0][fn] = MFMA16(a0, gf, aG[0][fn]);
                aG[1][fn] = MFMA16(a1, gf, aG[1][fn]);
                aU[0][fn] = MFMA16(a0, uf, aU[0][fn]);
                aU[1][fn] = MFMA16(a1, uf, aU[1][fn]);
            }
        }
        __syncthreads();
    }

    #pragma unroll
    for (int fm = 0; fm < 2; ++fm)
        #pragma unroll
        for (int fn = 0; fn < 4; ++fn)
            #pragma unroll
            for (int r = 0; r < 4; ++r) {
                int trow = mw*32 + fm*16 + lq*4 + r;
                int col  = nw*64 + fn*16 + lr;
                float g = aG[fm][fn][r], u = aU[fm][fn][r];
                hout[(size_t)trow * hpitch + col] = f2bf(g * u / (1.f + __expf(-g)));
            }
}

// ---------------------------------------------------------------- Kernel B: down-proj
// 64 tokens x 128 out-cols per block. bx<4096: routed (K=512, weighted atomicAdd);
// else shared (K=1024, atomicAdd w=1). out pre-zeroed by prep.
__global__ __launch_bounds__(256)
void moe_down(const short* __restrict__ h_r, const short* __restrict__ h_sh,
              const int* __restrict__ counts, const int* __restrict__ lists,
              const float* __restrict__ lw, const short* __restrict__ dw,
              const short* __restrict__ shdw, float* __restrict__ out) {
    __shared__ __align__(16) short Hs[64*64];     // 8 KB
    __shared__ __align__(16) short Ws[128*64];    // 16 KB
    __shared__ int toks[64];
    __shared__ float tws[64];
    const int bx = blockIdx.x, tid = threadIdx.x;
    const short *abase, *bbase; int apitch, K, n0;
    if (bx < 4096) {
        int e = bx >> 8, mt = (bx >> 3) & 31, nt = bx & 7;
        int cnt = counts[e];
        if (mt * 64 >= cnt) return;
        if (tid < 64) {
            int j = mt * 64 + tid;
            toks[tid] = (j < cnt) ? lists[e * T_TOK + j] : 0;
            tws[tid]  = (j < cnt) ? lw[e * T_TOK + j] : 0.f;
        }
        abase = h_r + ((size_t)e * T_TOK + mt * 64) * I_SZ;
        bbase = dw + (size_t)e * H_DIM * I_SZ + (size_t)(nt * 128) * I_SZ;
        apitch = I_SZ; K = I_SZ; n0 = nt * 128;
    } else {
        int b2 = bx - 4096, mt = b2 >> 3, nt = b2 & 7;
        if (tid < 64) { toks[tid] = mt * 64 + tid; tws[tid] = 1.f; }
        abase = h_sh + (size_t)(mt * 64) * 1024;
        bbase = shdw + (size_t)(nt * 128) * 1024;
        apitch = 1024; K = 1024; n0 = nt * 128;
    }
    __syncthreads();

    const int lane = tid & 63, wv = tid >> 6;
    const int mw = wv & 1, nw = wv >> 1;
    const int lr = lane & 15, lq = lane >> 4;
    const int l3 = lane >> 3, l7 = lane & 7;
    const int seg = (l7 ^ l3) * 8;

    const short* aA  = abase + (size_t)(wv*16     + l3) * apitch + seg;
    const short* aB  = abase + (size_t)(wv*16 + 8 + l3) * apitch + seg;
    const short* bS0 = bbase + (size_t)(wv*32      + l3) * apitch + seg;  // bpitch == apitch == K
    const short* bS1 = bbase + (size_t)(wv*32 + 8  + l3) * apitch + seg;
    const short* bS2 = bbase + (size_t)(wv*32 + 16 + l3) * apitch + seg;
    const short* bS3 = bbase + (size_t)(wv*32 + 24 + l3) * apitch + seg;
    short* ldsHA = &Hs[(wv*16    ) * 64]; short* ldsHB = &Hs[(wv*16 + 8) * 64];
    short* ldsW0 = &Ws[(wv*32     ) * 64]; short* ldsW1 = &Ws[(wv*32 + 8 ) * 64];
    short* ldsW2 = &Ws[(wv*32 + 16) * 64]; short* ldsW3 = &Ws[(wv*32 + 24) * 64];

    f32x4 acc[2][4];
    #pragma unroll
    for (int a = 0; a < 2; ++a)
        #pragma unroll
        for (int b = 0; b < 4; ++b) acc[a][b] = (f32x4){0.f,0.f,0.f,0.f};

    auto chunk = [&](int kc) {
        gld16(aA + kc, ldsHA);  gld16(aB + kc, ldsHB);
        gld16(bS0 + kc, ldsW0); gld16(bS1 + kc, ldsW1);
        gld16(bS2 + kc, ldsW2); gld16(bS3 + kc, ldsW3);
        __syncthreads();
        #pragma unroll
        for (int kk = 0; kk < 64; kk += 32) {
            const int kf = kk + lq * 8;
            bfrag a0 = *(const bfrag*)&Hs[lds_idx(mw*32 + lr,      kf)];
            bfrag a1 = *(const bfrag*)&Hs[lds_idx(mw*32 + 16 + lr, kf)];
            #pragma unroll
            for (int fn = 0; fn < 4; ++fn) {
                bfrag bf = *(const bfrag*)&Ws[lds_idx(nw*64 + fn*16 + lr, kf)];
                acc[0][fn] = MFMA16(a0, bf, acc[0][fn]);
                acc[1][fn] = MFMA16(a1, bf, acc[1][fn]);
            }
        }
        __syncthreads();
    };
    #pragma unroll
    for (int c = 0; c < 8; ++c) chunk(c * 64);
    if (K == 1024) {
        #pragma unroll
        for (int c = 8; c < 16; ++c) chunk(c * 64);
    }

    #pragma unroll
    for (int fm = 0; fm < 2; ++fm)
        #pragma unroll
        for (int fn = 0; fn < 4; ++fn)
            #pragma unroll
            for (int r = 0; r < 4; ++r) {
                int trow = mw*32 + fm*16 + lq*4 + r;
                int col  = n0 + nw*64 + fn*16 + lr;
                float w = tws[trow];
                if (w != 0.f)
                    atomicAdd(out + (size_t)toks[trow] * H_DIM + col, acc[fm][fn][r] * w);
            }
}

// ---------------------------------------------------------------- fallback (fused, fp32 weights)
__global__ void zero_kernel(float* __restrict__ out, int n4, int* __restrict__ counts) {
    int i = blockIdx.x * blockDim.x + threadIdx.x;
    if (i < n4) {
        float4 z = {0.f, 0.f, 0.f, 0.f};
        *(float4*)(out + (size_t)i * 4) = z;
    }
    if (blockIdx.x == 0 && threadIdx.x < E_EXP) counts[threadIdx.x] = 0;
}

__global__ __launch_bounds__(256)
void router_fb(const float* __restrict__ x, const float* __restrict__ rw,
               const float* __restrict__ ebias, int* __restrict__ counts,
               int* __restrict__ lists, float* __restrict__ lweights) {
    __shared__ float part[256];
    __shared__ float lg[RTOK][E_EXP];
    const int tid = threadIdx.x;
    const int t0 = blockIdx.x * RTOK;
    {
        int half = tid >> 7;
        int e    = (tid >> 3) & 15;
        int tok  = tid & 7;
        const float* wr = rw + (size_t)e * H_DIM + half * 512;
        const float* xr = x + (size_t)(t0 + tok) * H_DIM + half * 512;
        float acc = 0.f;
        #pragma unroll 4
        for (int k = 0; k < 512; k += 4) {
            float4 w  = *(const float4*)(wr + k);
            float4 xv = *(const float4*)(xr + k);
            acc += w.x * xv.x + w.y * xv.y + w.z * xv.z + w.w * xv.w;
        }
        part[tid] = acc;
    }
    __syncthreads();
    if (tid < 128) lg[tid & 7][tid >> 3] = part[tid] + part[tid + 128];
    __syncthreads();
    if (tid >= RTOK) return;
    route_token(t0 + tid, lg[tid], ebias, counts, lists, lweights);
}

__device__ __forceinline__ bfrag load_wfrag_f(const float* p) {
    float4 a = *(const float4*)(p);
    float4 b = *(const float4*)(p + 4);
    bfrag r;
    r[0]=f2bf(a.x); r[1]=f2bf(a.y); r[2]=f2bf(a.z); r[3]=f2bf(a.w);
    r[4]=f2bf(b.x); r[5]=f2bf(b.y); r[6]=f2bf(b.z); r[7]=f2bf(b.w);
    return r;
}

#define TM 32
__global__ __launch_bounds__(256)
void moe_gemm_fb(const float* __restrict__ x,
                 const float* __restrict__ gate_w, const float* __restrict__ up_w,
                 const float* __restrict__ down_w, const float* __restrict__ sh_gate,
                 const float* __restrict__ sh_up, const float* __restrict__ sh_down,
                 const int* __restrict__ counts, const int* __restrict__ lists,
                 const float* __restrict__ lweights, float* __restrict__ out) {
    const int bx = blockIdx.x;
    const int e = bx >> 6;
    const int tile = bx & 63;
    int ntok; const float *gp, *upp, *dpp; int dpitch;
    if (e < E_EXP) {
        ntok = counts[e];
        gp  = gate_w + (size_t)e * I_SZ * H_DIM;
        upp = up_w   + (size_t)e * I_SZ * H_DIM;
        dpp = down_w + (size_t)e * H_DIM * I_SZ;
        dpitch = I_SZ;
    } else {
        int s = e - E_EXP;
        ntok = T_TOK;
        gp  = sh_gate + (size_t)s * I_SZ * H_DIM;
        upp = sh_up   + (size_t)s * I_SZ * H_DIM;
        dpp = sh_down + (size_t)s * I_SZ;
        dpitch = 2 * I_SZ;
    }
    const int start = tile * TM;
    if (start >= ntok) return;

    __shared__ __align__(16) short Xs2[TM][H_DIM + 8];
    __shared__ __align__(16) short Hs2[TM][I_SZ + 8];
    __shared__ int   toks[TM];
    __shared__ float tws[TM];

    const int tid = threadIdx.x;
    if (tid < TM) {
        int j = start + tid;
        int tok = 0; float w = 0.f;
        if (j < ntok) {
            if (e < E_EXP) { tok = lists[e * T_TOK + j]; w = lweights[e * T_TOK + j]; }
            else           { tok = j;                    w = 1.0f; }
        }
        toks[tid] = tok; tws[tid] = w;
    }
    __syncthreads();
    {
        int r = tid >> 3;
        int c0 = (tid & 7) * 128;
        const float* xr = x + (size_t)toks[r] * H_DIM + c0;
        #pragma unroll
        for (int c = 0; c < 128; c += 4) {
            float4 v = *(const float4*)(xr + c);
            short4 s = { f2bf(v.x), f2bf(v.y), f2bf(v.z), f2bf(v.w) };
            *(short4*)&Xs2[r][c0 + c] = s;
        }
    }
    __syncthreads();

    const int lane = tid & 63;
    const int wv   = tid >> 6;
    const int lr   = lane & 15;
    const int lq   = lane >> 4;
    const int ko   = lq * 8;

    for (int it = 0; it < I_SZ / 64; ++it) {
        const int i0 = wv * (I_SZ / 4) + it * 16;
        const float* grow = gp  + (size_t)(i0 + lr) * H_DIM;
        const float* urow = upp + (size_t)(i0 + lr) * H_DIM;
        f32x4 aG0 = {0.f,0.f,0.f,0.f}, aU0 = {0.f,0.f,0.f,0.f};
        f32x4 aG1 = {0.f,0.f,0.f,0.f}, aU1 = {0.f,0.f,0.f,0.f};
        for (int k0 = 0; k0 < H_DIM; k0 += 32) {
            bfrag bg = load_wfrag_f(grow + k0 + ko);
            bfrag bu = load_wfrag_f(urow + k0 + ko);
            bfrag a0 = *(const bfrag*)&Xs2[lr][k0 + ko];
            bfrag a1 = *(const bfrag*)&Xs2[lr + 16][k0 + ko];
            aG0 = MFMA16(a0, bg, aG0);
            aG1 = MFMA16(a1, bg, aG1);
            aU0 = MFMA16(a0, bu, aU0);
            aU1 = MFMA16(a1, bu, aU1);
        }
        #pragma unroll
        for (int r = 0; r < 4; ++r) {
            const int trow = lq * 4 + r;
            float g0 = aG0[r], u0 = aU0[r];
            Hs2[trow][i0 + lr] = f2bf(g0 * u0 / (1.f + __expf(-g0)));
            float g1 = aG1[r], u1 = aU1[r];
            Hs2[trow + 16][i0 + lr] = f2bf(g1 * u1 / (1.f + __expf(-g1)));
        }
    }
    __syncthreads();

    for (int ct = 0; ct < H_DIM / 64; ++ct) {
        const int c0 = wv * (H_DIM / 4) + ct * 16;
        const float* drow = dpp + (size_t)(c0 + lr) * dpitch;
        f32x4 a0 = {0.f,0.f,0.f,0.f}, a1 = {0.f,0.f,0.f,0.f};
        for (int k0 = 0; k0 < I_SZ; k0 += 32) {
            bfrag bd = load_wfrag_f(drow + k0 + ko);
            bfrag h0 = *(const bfrag*)&Hs2[lr][k0 + ko];
            bfrag h1 = *(const bfrag*)&Hs2[lr + 16][k0 + ko];
            a0 = MFMA16(h0, bd, a0);
            a1 = MFMA16(h1, bd, a1);
        }
        #pragma unroll
        for (int r = 0; r < 4; ++r) {
            const int trow = lq * 4 + r;
            float w0 = tws[trow], w1 = tws[trow + 16];
            if (w0 != 0.f) atomicAdd(out + (size_t)toks[trow] * H_DIM + c0 + lr, a0[r] * w0);
            if (w1 != 0.f) atomicAdd(out + (size_t)toks[trow + 16] * H_DIM + c0 + lr, a1[r] * w1);
        }
    }
}

// ---------------------------------------------------------------- launch
extern "C" void kernel_launch(void* const* d_in, const int* in_sizes, int n_in,
                              void* d_out, int out_size, void* d_ws, size_t ws_size,
                              hipStream_t stream) {
    const float* x     = (const float*)d_in[0];
    const float* rw    = (const float*)d_in[1];
    const float* ebias = (const float*)d_in[2];
    const float* gate_w = (const float*)d_in[3];
    const float* up_w   = (const float*)d_in[4];
    const float* down_w = (const float*)d_in[5];
    const float* shg    = (const float*)d_in[6];
    const float* shu    = (const float*)d_in[7];
    const float* shd    = (const float*)d_in[8];
    float* out = (float*)d_out;

    char* ws = (char*)d_ws;
    int*   counts = (int*)ws;                       // 64 B used
    int*   lists  = (int*)(ws + 1024);              // 16*2048 ints  = 128 KB
    float* lw     = (float*)(ws + 1024 + 131072);   // 16*2048 float = 128 KB
    size_t off = 1024 + 131072 + 131072;            // 263168

    const size_t n_gu = (size_t)E_EXP * I_SZ * H_DIM;   // 8388608
    const size_t n_sh = (size_t)H_DIM * 1024;           // 1048576
    const size_t n_x  = (size_t)T_TOK * H_DIM;          // 2097152

    short* g_bf  = (short*)(ws + off); off += n_gu * 2;
    short* u_bf  = (short*)(ws + off); off += n_gu * 2;
    short* d_bf  = (short*)(ws + off); off += n_gu * 2;
    short* sg_bf = (short*)(ws + off); off += n_sh * 2;
    short* su_bf = (short*)(ws + off); off += n_sh * 2;
    short* sd_bf = (short*)(ws + off); off += n_sh * 2;
    short* x_bf  = (short*)(ws + off); off += n_x * 2;
    short* h_r   = (short*)(ws + off); off += (size_t)E_EXP * T_TOK * I_SZ * 2;  // 32 MB
    short* h_sh  = (short*)(ws + off); off += (size_t)T_TOK * 1024 * 2;          // 4 MB
    const size_t need = off;

    if (ws_size >= need) {
        hipMemsetAsync(counts, 0, 64, stream);
        prep_kernel<<<CVT_BLKS + RT_BLKS + ZERO_BLKS, 256, 0, stream>>>(
            x, rw, ebias, gate_w, up_w, down_w, shg, shu, shd,
            g_bf, u_bf, d_bf, sg_bf, su_bf, sd_bf, x_bf,
            counts, lists, lw, out, out_size);
        moe_gateup<<<2048 + 256, 256, 0, stream>>>(x_bf, counts, lists, g_bf, u_bf,
                                                   sg_bf, su_bf, h_r, h_sh);
        moe_down<<<4096 + 256, 256, 0, stream>>>(h_r, h_sh, counts, lists, lw,
                                                 d_bf, sd_bf, out);
    } else {
        zero_kernel<<<(out_size / 4 + 255) / 256, 256, 0, stream>>>(out, out_size / 4, counts);
        router_fb<<<T_TOK / RTOK, 256, 0, stream>>>(x, rw, ebias, counts, lists, lw);
        moe_gemm_fb<<<(E_EXP + 2) * 64, 256, 0, stream>>>(x, gate_w, up_w, down_w,
                                                          shg, shu, shd, counts, lists, lw, out);
    }
}